// Round 7
// baseline (196.800 us; speedup 1.0000x reference)
//
#include <hip/hip_runtime.h>
#include <hip/hip_bf16.h>

// B=8, NH=8, KS=VS=64, HW=1024, C=1536, GROUPS=24. pair = b*8+h (64 pairs).
// gn_partial -> pack (Qn/Kn [s][c], Vn [c][s], bf16) -> attn:
//   S^T flash, 2-wave blocks, 2-way split-K, rotated software pipeline
//   (PV lagged one tile), lane-contiguous P staging, full-line stores.

typedef __attribute__((ext_vector_type(8))) short bf16x8;
typedef __attribute__((ext_vector_type(4))) float f32x4;
typedef unsigned short u16;
typedef unsigned int u32;

#define SM_SCALE 0.18033688f   // 0.125 * log2(e)
#define SM_OFF   8.0f          // fixed softmax offset (shift-invariant)

__device__ __forceinline__ u32 pack2(float a, float b) {  // (bf(b)<<16)|bf(a)
    union { float f; u32 u; } ua, ub; ua.f = a; ub.f = b;
    return __builtin_amdgcn_perm(ub.u + 0x8000u, ua.u + 0x8000u, 0x07060302u);
}
union PB { uint4 u; bf16x8 v; };

// ---- Kernel 1: partial GN stats. 1536 blocks = 8 slices per (b,group).
__global__ __launch_bounds__(256) void gn_partial(const float* __restrict__ x,
                                                  float* __restrict__ partials) {
    int blk = blockIdx.x;
    const float4* p = (const float4*)(x + (size_t)blk * 8192);
    int t = threadIdx.x;
    float s1a = 0.f, s2a = 0.f, s1b = 0.f, s2b = 0.f;
#pragma unroll
    for (int i = 0; i < 8; i += 2) {
        float4 va = p[t + i * 256];
        float4 vb = p[t + (i + 1) * 256];
        s1a += va.x + va.y + va.z + va.w;
        s2a += va.x*va.x + va.y*va.y + va.z*va.z + va.w*va.w;
        s1b += vb.x + vb.y + vb.z + vb.w;
        s2b += vb.x*vb.x + vb.y*vb.y + vb.z*vb.z + vb.w*vb.w;
    }
    float s1 = s1a + s1b, s2 = s2a + s2b;
    for (int off = 32; off > 0; off >>= 1) {
        s1 += __shfl_down(s1, off);
        s2 += __shfl_down(s2, off);
    }
    __shared__ float a1[4], a2[4];
    int wave = t >> 6, lane = t & 63;
    if (lane == 0) { a1[wave] = s1; a2[wave] = s2; }
    __syncthreads();
    if (t == 0) {
        partials[blk * 2 + 0] = a1[0] + a1[1] + a1[2] + a1[3];
        partials[blk * 2 + 1] = a2[0] + a2[1] + a2[2] + a2[3];
    }
}

__device__ __forceinline__ void group_stats(const float* __restrict__ partials,
                                            int bg, float& mean, float& rstd) {
    float s1 = 0.f, s2 = 0.f;
#pragma unroll
    for (int j = 0; j < 8; ++j) {
        s1 += partials[(bg * 8 + j) * 2 + 0];
        s2 += partials[(bg * 8 + j) * 2 + 1];
    }
    mean = s1 * (1.f / 65536.f);
    float var = s2 * (1.f / 65536.f) - mean * mean;
    rstd = rsqrtf(var + 1e-5f);
}

// ---- Kernel 2: normalize + pack. Coalesced x loads; K,Q -> [s][c] via
// paired-u32 LDS transpose (odd stride = conflict-free); V -> [c][s] direct.
__global__ __launch_bounds__(256) void pack_kernel(
    const float* __restrict__ x, const float* __restrict__ gamma,
    const float* __restrict__ beta, const float* __restrict__ partials,
    u16* __restrict__ Qn, u16* __restrict__ Kn, u16* __restrict__ Vn)
{
    const int st = blockIdx.x >> 6, pair = blockIdx.x & 63;
    const int b = pair >> 3, h = pair & 7;
    const float* xb = x + (size_t)b * 1536 * 1024;
    float ms[3], rs[3];
    group_stats(partials, b * 24 + 3 * h + 0, ms[0], rs[0]);
    group_stats(partials, b * 24 + 3 * h + 1, ms[1], rs[1]);
    group_stats(partials, b * 24 + 3 * h + 2, ms[2], rs[2]);

    const int t = threadIdx.x;
    __shared__ u32 Tsh[64][33];

    const int cp = t >> 4;          // 0..15 channel-pair
    const int s4 = (t & 15) * 4;
    const int sgl = st * 64 + s4;

    for (int t2 = 0; t2 < 2; ++t2) {       // K then Q
        if (t2) __syncthreads();
#pragma unroll
        for (int dc = 0; dc < 2; ++dc) {
            int cg0 = h * 192 + t2 * 64 + dc * 32 + cp * 2;
            float4 va = *(const float4*)(xb + (size_t)cg0 * 1024 + sgl);
            float4 vb = *(const float4*)(xb + (size_t)(cg0 + 1) * 1024 + sgl);
            float w0 = gamma[cg0] * rs[t2],     b0 = beta[cg0] - ms[t2] * w0;
            float w1 = gamma[cg0 + 1] * rs[t2], b1 = beta[cg0 + 1] - ms[t2] * w1;
            int col = dc * 16 + cp;
            Tsh[s4 + 0][col] = pack2(va.x * w0 + b0, vb.x * w1 + b1);
            Tsh[s4 + 1][col] = pack2(va.y * w0 + b0, vb.y * w1 + b1);
            Tsh[s4 + 2][col] = pack2(va.z * w0 + b0, vb.z * w1 + b1);
            Tsh[s4 + 3][col] = pack2(va.w * w0 + b0, vb.w * w1 + b1);
        }
        __syncthreads();
        u16* dst = (t2 ? Qn : Kn) + (size_t)pair * 65536 + (size_t)st * 64 * 64;
#pragma unroll
        for (int p = 0; p < 2; ++p) {
            int row = p * 32 + (t >> 3);
            int c8 = (t & 7) * 4;
            uint4 o;
            o.x = Tsh[row][c8 + 0]; o.y = Tsh[row][c8 + 1];
            o.z = Tsh[row][c8 + 2]; o.w = Tsh[row][c8 + 3];
            *(uint4*)(dst + (size_t)row * 64 + c8 * 2) = o;
        }
    }
    // V: native [c][s], no LDS.
    {
#pragma unroll
        for (int dc = 0; dc < 4; ++dc) {
            int c = dc * 16 + (t >> 4);
            int cg = h * 192 + 128 + c;
            float4 v = *(const float4*)(xb + (size_t)cg * 1024 + sgl);
            float wsc = gamma[cg] * rs[2];
            float bsc = beta[cg] - ms[2] * wsc;
            uint2 o;
            o.x = pack2(v.x * wsc + bsc, v.y * wsc + bsc);
            o.y = pack2(v.z * wsc + bsc, v.w * wsc + bsc);
            *(uint2*)(Vn + (size_t)pair * 65536 + (size_t)c * 1024 + sgl) = o;
        }
    }
}

// ---------- attn helpers ----------
__device__ __forceinline__ void load_ak(const u16* __restrict__ Kp, int kt,
                                        int li, int grp, bf16x8 ak[4][2]) {
    const u16* kr = Kp + (size_t)(kt * 64 + li) * 64 + grp * 8;
#pragma unroll
    for (int kf = 0; kf < 4; ++kf) {
        ak[kf][0] = *(const bf16x8*)(kr + kf * 1024);
        ak[kf][1] = *(const bf16x8*)(kr + kf * 1024 + 32);
    }
}
__device__ __forceinline__ void load_av(const u16* __restrict__ Vp, int kt,
                                        int li, int grp, bf16x8 av[4][2]) {
    const u16* vr = Vp + (size_t)li * 1024 + kt * 64 + grp * 8;
#pragma unroll
    for (int vf = 0; vf < 4; ++vf) {
        av[vf][0] = *(const bf16x8*)(vr + vf * 16384);
        av[vf][1] = *(const bf16x8*)(vr + vf * 16384 + 32);
    }
}
__device__ __forceinline__ void do_S(const bf16x8 ak[4][2], const bf16x8 bq[2][2],
                                     f32x4 sf[2][4]) {
#pragma unroll
    for (int qf = 0; qf < 2; ++qf)
#pragma unroll
        for (int kf = 0; kf < 4; ++kf) {
            f32x4 acc = f32x4{0.f, 0.f, 0.f, 0.f};
            acc = __builtin_amdgcn_mfma_f32_16x16x32_bf16(ak[kf][0], bq[qf][0], acc, 0, 0, 0);
            acc = __builtin_amdgcn_mfma_f32_16x16x32_bf16(ak[kf][1], bq[qf][1], acc, 0, 0, 0);
            sf[qf][kf] = acc;
        }
}
__device__ __forceinline__ void do_expP(const f32x4 sf[2][4], float lsum[2],
                                        u32* prow0, u32* prow1, int grp) {
#pragma unroll
    for (int qf = 0; qf < 2; ++qf) {
        u32 pr[8];
#pragma unroll
        for (int kf = 0; kf < 4; ++kf) {
            float p0 = exp2f(__builtin_fmaf(sf[qf][kf][0], SM_SCALE, -SM_OFF));
            float p1 = exp2f(__builtin_fmaf(sf[qf][kf][1], SM_SCALE, -SM_OFF));
            float p2 = exp2f(__builtin_fmaf(sf[qf][kf][2], SM_SCALE, -SM_OFF));
            float p3 = exp2f(__builtin_fmaf(sf[qf][kf][3], SM_SCALE, -SM_OFF));
            lsum[qf] += (p0 + p1) + (p2 + p3);
            pr[kf * 2 + 0] = pack2(p0, p1);
            pr[kf * 2 + 1] = pack2(p2, p3);
        }
        u32* pw = (qf ? prow1 : prow0) + grp * 8;
        *(uint4*)(pw + 0) = uint4{pr[0], pr[1], pr[2], pr[3]};
        *(uint4*)(pw + 4) = uint4{pr[4], pr[5], pr[6], pr[7]};
    }
}
__device__ __forceinline__ void do_PV(const bf16x8 av[4][2],
                                      const u32* prow0, const u32* prow1,
                                      int grp, f32x4 oacc[2][4]) {
    const int g1 = (2 * grp) & 3, g2 = (2 * grp + 1) & 3;
    const int koff = 2 * (grp >> 1);
#pragma unroll
    for (int qf = 0; qf < 2; ++qf) {
        const u32* rp = qf ? prow1 : prow0;
#pragma unroll
        for (int kh = 0; kh < 2; ++kh) {
            uint2 a = *(const uint2*)(rp + g1 * 8 + 4 * kh + koff);
            uint2 b = *(const uint2*)(rp + g2 * 8 + 4 * kh + koff);
            PB pb; pb.u = uint4{a.x, a.y, b.x, b.y};
#pragma unroll
            for (int vf = 0; vf < 4; ++vf)
                oacc[qf][vf] = __builtin_amdgcn_mfma_f32_16x16x32_bf16(av[vf][kh], pb.v, oacc[qf][vf], 0, 0, 0);
        }
    }
}

// ---- Kernel 3: flash attention. Grid 2048 (qt*64+pair), 128 thr = 2 waves.
// Wave w does K-half w for the block's 32 queries; rotated pipeline.
__global__ __launch_bounds__(128, 3) void attn_kernel(
    const u16* __restrict__ Qn, const u16* __restrict__ Kn,
    const u16* __restrict__ Vn, float* __restrict__ out)
{
    const int bid = blockIdx.x;
    const int qt = bid >> 6;        // 0..31
    const int pair = bid & 63;
    const int tid = threadIdx.x;
    const int w = tid >> 6;
    const int lane = tid & 63;
    const int grp = lane >> 4, li = lane & 15;

    __shared__ union {
        u32 pt[2][2][16][36];       // P staging: [wave][qf][q=li][8 dw @ grp*8]
        float ot[2][64][36];        // epilogue: [wave][v][q] partial O
    } sm;
    __shared__ float lred[2][2][16];

    const u16* Qp = Qn + (size_t)pair * 65536;
    const u16* Kp = Kn + (size_t)pair * 65536;
    const u16* Vp = Vn + (size_t)pair * 65536;

    // Q B-frags: B[n=q(li)][k=c]
    bf16x8 bq[2][2];
#pragma unroll
    for (int qf = 0; qf < 2; ++qf) {
        const u16* qrow = Qp + (size_t)(qt * 32 + qf * 16 + li) * 64 + grp * 8;
        bq[qf][0] = *(const bf16x8*)(qrow);
        bq[qf][1] = *(const bf16x8*)(qrow + 32);
    }

    f32x4 oacc[2][4];
#pragma unroll
    for (int qf = 0; qf < 2; ++qf)
#pragma unroll
        for (int vf = 0; vf < 4; ++vf) oacc[qf][vf] = f32x4{0.f, 0.f, 0.f, 0.f};
    float lsum[2] = {0.f, 0.f};

    u32* prow0 = &sm.pt[w][0][li][0];
    u32* prow1 = &sm.pt[w][1][li][0];
    const int kt0 = w * 8;

    bf16x8 ak[4][2], av[4][2];
    f32x4 sf[2][4];

    // ---- prologue: S[0], then loads for next stage, then exp/P[0]
    load_ak(Kp, kt0, li, grp, ak);
    do_S(ak, bq, sf);
    load_ak(Kp, kt0 + 1, li, grp, ak);
    load_av(Vp, kt0, li, grp, av);
    do_expP(sf, lsum, prow0, prow1, grp);

#pragma unroll 1
    for (int i = 1; i < 8; ++i) {
        do_PV(av, prow0, prow1, grp, oacc);    // tile i-1 (av + P in LDS)
        do_S(ak, bq, sf);                      // tile i  (ak dies here)
        if (i < 7) load_ak(Kp, kt0 + i + 1, li, grp, ak);
        load_av(Vp, kt0 + i, li, grp, av);
        do_expP(sf, lsum, prow0, prow1, grp);  // writes P[i] (after PV read P[i-1])
    }
    do_PV(av, prow0, prow1, grp, oacc);        // trailing tile 7

    // ---- l reduce across quads; publish; O to LDS; full-line stores
#pragma unroll
    for (int qf = 0; qf < 2; ++qf) {
        lsum[qf] += __shfl_xor(lsum[qf], 16);
        lsum[qf] += __shfl_xor(lsum[qf], 32);
    }
    __syncthreads();                 // all pt use done before aliasing as ot
    if (grp == 0) { lred[w][0][li] = lsum[0]; lred[w][1][li] = lsum[1]; }
#pragma unroll
    for (int qf = 0; qf < 2; ++qf)
#pragma unroll
        for (int vf = 0; vf < 4; ++vf)
#pragma unroll
            for (int r = 0; r < 4; ++r)
                sm.ot[w][vf * 16 + grp * 4 + r][qf * 16 + li] = oacc[qf][vf][r];
    __syncthreads();

    const int q = lane & 31;
    const int vb = w * 32 + (lane >> 5);
    const float invl = 1.f / (lred[0][q >> 4][q & 15] + lred[1][q >> 4][q & 15]);
    float* ob = out + (size_t)pair * 65536 + qt * 32 + q;
#pragma unroll
    for (int it = 0; it < 16; ++it) {
        int v = vb + it * 2;
        float o = (sm.ot[0][v][q] + sm.ot[1][v][q]) * invl;
        ob[(size_t)v * 1024] = o;
    }
}

extern "C" void kernel_launch(void* const* d_in, const int* in_sizes, int n_in,
                              void* d_out, int out_size, void* d_ws, size_t ws_size,
                              hipStream_t stream) {
    const float* x     = (const float*)d_in[0];
    const float* gamma = (const float*)d_in[1];
    const float* beta  = (const float*)d_in[2];
    float* out = (float*)d_out;

    float* partials = (float*)d_ws;                       // 3072 f32
    u16* Qn = (u16*)((char*)d_ws + 32768);                // 8.4 MB
    u16* Kn = Qn + (size_t)64 * 65536;                    // 8.4 MB
    u16* Vn = Kn + (size_t)64 * 65536;                    // 8.4 MB (~25.2 MB total)

    gn_partial<<<1536, 256, 0, stream>>>(x, partials);
    pack_kernel<<<1024, 256, 0, stream>>>(x, gamma, beta, partials, Qn, Kn, Vn);
    attn_kernel<<<2048, 128, 0, stream>>>(Qn, Kn, Vn, out);
}

// Round 8
// 134.641 us; speedup vs baseline: 1.4617x; 1.4617x over previous
//
#include <hip/hip_runtime.h>
#include <hip/hip_bf16.h>

// B=8, NH=8, KS=VS=64, HW=1024, C=1536, GROUPS=24. pair = b*8+h (64 pairs).
// gn_partial -> pack (Qn/Kn [s][c], Vn [c][s], bf16) -> attn:
//   m97-style block staging: 4-wave blocks own 128 q; K/V tiles staged to
//   LDS (XOR-swizzled, conflict-free ds_read_b128), register prefetch of
//   next tile under compute, one barrier per tile. Fixed-offset softmax.

typedef __attribute__((ext_vector_type(8))) short bf16x8;
typedef __attribute__((ext_vector_type(4))) float f32x4;
typedef unsigned short u16;
typedef unsigned int u32;

#define SM_SCALE 0.18033688f   // 0.125 * log2(e)
#define SM_OFF   8.0f          // fixed softmax offset (shift-invariant)

__device__ __forceinline__ u32 pack2(float a, float b) {  // (bf(b)<<16)|bf(a)
    union { float f; u32 u; } ua, ub; ua.f = a; ub.f = b;
    return __builtin_amdgcn_perm(ub.u + 0x8000u, ua.u + 0x8000u, 0x07060302u);
}
union BB { uint4 u; bf16x8 v; };

// ---- Kernel 1: partial GN stats. 1536 blocks = 8 slices per (b,group).
__global__ __launch_bounds__(256) void gn_partial(const float* __restrict__ x,
                                                  float* __restrict__ partials) {
    int blk = blockIdx.x;
    const float4* p = (const float4*)(x + (size_t)blk * 8192);
    int t = threadIdx.x;
    float s1a = 0.f, s2a = 0.f, s1b = 0.f, s2b = 0.f;
#pragma unroll
    for (int i = 0; i < 8; i += 2) {
        float4 va = p[t + i * 256];
        float4 vb = p[t + (i + 1) * 256];
        s1a += va.x + va.y + va.z + va.w;
        s2a += va.x*va.x + va.y*va.y + va.z*va.z + va.w*va.w;
        s1b += vb.x + vb.y + vb.z + vb.w;
        s2b += vb.x*vb.x + vb.y*vb.y + vb.z*vb.z + vb.w*vb.w;
    }
    float s1 = s1a + s1b, s2 = s2a + s2b;
    for (int off = 32; off > 0; off >>= 1) {
        s1 += __shfl_down(s1, off);
        s2 += __shfl_down(s2, off);
    }
    __shared__ float a1[4], a2[4];
    int wave = t >> 6, lane = t & 63;
    if (lane == 0) { a1[wave] = s1; a2[wave] = s2; }
    __syncthreads();
    if (t == 0) {
        partials[blk * 2 + 0] = a1[0] + a1[1] + a1[2] + a1[3];
        partials[blk * 2 + 1] = a2[0] + a2[1] + a2[2] + a2[3];
    }
}

__device__ __forceinline__ void group_stats(const float* __restrict__ partials,
                                            int bg, float& mean, float& rstd) {
    float s1 = 0.f, s2 = 0.f;
#pragma unroll
    for (int j = 0; j < 8; ++j) {
        s1 += partials[(bg * 8 + j) * 2 + 0];
        s2 += partials[(bg * 8 + j) * 2 + 1];
    }
    mean = s1 * (1.f / 65536.f);
    float var = s2 * (1.f / 65536.f) - mean * mean;
    rstd = rsqrtf(var + 1e-5f);
}

// ---- Kernel 2: normalize + pack. Coalesced x loads; K,Q -> [s][c] via
// paired-u32 LDS transpose (odd stride = conflict-free); V -> [c][s] direct.
__global__ __launch_bounds__(256) void pack_kernel(
    const float* __restrict__ x, const float* __restrict__ gamma,
    const float* __restrict__ beta, const float* __restrict__ partials,
    u16* __restrict__ Qn, u16* __restrict__ Kn, u16* __restrict__ Vn)
{
    const int st = blockIdx.x >> 6, pair = blockIdx.x & 63;
    const int b = pair >> 3, h = pair & 7;
    const float* xb = x + (size_t)b * 1536 * 1024;
    float ms[3], rs[3];
    group_stats(partials, b * 24 + 3 * h + 0, ms[0], rs[0]);
    group_stats(partials, b * 24 + 3 * h + 1, ms[1], rs[1]);
    group_stats(partials, b * 24 + 3 * h + 2, ms[2], rs[2]);

    const int t = threadIdx.x;
    __shared__ u32 Tsh[64][33];

    const int cp = t >> 4;          // 0..15 channel-pair
    const int s4 = (t & 15) * 4;
    const int sgl = st * 64 + s4;

    for (int t2 = 0; t2 < 2; ++t2) {       // K then Q
        if (t2) __syncthreads();
#pragma unroll
        for (int dc = 0; dc < 2; ++dc) {
            int cg0 = h * 192 + t2 * 64 + dc * 32 + cp * 2;
            float4 va = *(const float4*)(xb + (size_t)cg0 * 1024 + sgl);
            float4 vb = *(const float4*)(xb + (size_t)(cg0 + 1) * 1024 + sgl);
            float w0 = gamma[cg0] * rs[t2],     b0 = beta[cg0] - ms[t2] * w0;
            float w1 = gamma[cg0 + 1] * rs[t2], b1 = beta[cg0 + 1] - ms[t2] * w1;
            int col = dc * 16 + cp;
            Tsh[s4 + 0][col] = pack2(va.x * w0 + b0, vb.x * w1 + b1);
            Tsh[s4 + 1][col] = pack2(va.y * w0 + b0, vb.y * w1 + b1);
            Tsh[s4 + 2][col] = pack2(va.z * w0 + b0, vb.z * w1 + b1);
            Tsh[s4 + 3][col] = pack2(va.w * w0 + b0, vb.w * w1 + b1);
        }
        __syncthreads();
        u16* dst = (t2 ? Qn : Kn) + (size_t)pair * 65536 + (size_t)st * 64 * 64;
#pragma unroll
        for (int p = 0; p < 2; ++p) {
            int row = p * 32 + (t >> 3);
            int c8 = (t & 7) * 4;
            uint4 o;
            o.x = Tsh[row][c8 + 0]; o.y = Tsh[row][c8 + 1];
            o.z = Tsh[row][c8 + 2]; o.w = Tsh[row][c8 + 3];
            *(uint4*)(dst + (size_t)row * 64 + c8 * 2) = o;
        }
    }
    // V: native [c][s], no LDS.
    {
#pragma unroll
        for (int dc = 0; dc < 4; ++dc) {
            int c = dc * 16 + (t >> 4);
            int cg = h * 192 + 128 + c;
            float4 v = *(const float4*)(xb + (size_t)cg * 1024 + sgl);
            float wsc = gamma[cg] * rs[2];
            float bsc = beta[cg] - ms[2] * wsc;
            uint2 o;
            o.x = pack2(v.x * wsc + bsc, v.y * wsc + bsc);
            o.y = pack2(v.z * wsc + bsc, v.w * wsc + bsc);
            *(uint2*)(Vn + (size_t)pair * 65536 + (size_t)c * 1024 + sgl) = o;
        }
    }
}

// ---- Kernel 3: flash attention, block-staged LDS tiles.
// Grid 512: bid = qt*64 + pair (qt 0..7) -> bid%8 = pair%8 (XCD locality).
// Block = 256 thr = 4 waves; block owns 128 queries (32/wave). Per K-tile:
// prefetch next tile into 4 staging uint4/thread, compute current from LDS.
__global__ __launch_bounds__(256, 2) void attn_kernel(
    const u16* __restrict__ Qn, const u16* __restrict__ Kn,
    const u16* __restrict__ Vn, float* __restrict__ out)
{
    const int bid = blockIdx.x;
    const int qt = bid >> 6;        // 0..7
    const int pair = bid & 63;
    const int tid = threadIdx.x;
    const int w = tid >> 6;
    const int lane = tid & 63;
    const int grp = lane >> 4, li = lane & 15;

    __shared__ uint4 KT[2][512];            // [buf][row*8 + (chunk^(row&7))]
    __shared__ uint4 VT[2][512];
    __shared__ u32 PT[4][2][16][36];        // per-wave P [wave][qf][q=li][..]

    const u16* Qp = Qn + (size_t)pair * 65536;
    const u16* Kp = Kn + (size_t)pair * 65536;
    const u16* Vp = Vn + (size_t)pair * 65536;

    // staging geometry: thread t covers 16B chunks j = 2t, 2t+1 (512 total)
    const int j0 = tid * 2;
    const int srow = j0 >> 3;               // 0..63
    const int sch  = j0 & 7;                // even
    const int sx   = srow & 7;
    const int idx0 = srow * 8 + (sch ^ sx);
    const int idx1 = srow * 8 + ((sch + 1) ^ sx);

    // Q B-frags: B[n=q(li)][k=c]
    const int q0 = qt * 128 + w * 32;
    bf16x8 bq[2][2];
#pragma unroll
    for (int qf = 0; qf < 2; ++qf) {
        const u16* qrow = Qp + (size_t)(q0 + qf * 16 + li) * 64 + grp * 8;
        bq[qf][0] = *(const bf16x8*)(qrow);
        bq[qf][1] = *(const bf16x8*)(qrow + 32);
    }

    f32x4 oacc[2][4];
#pragma unroll
    for (int qf = 0; qf < 2; ++qf)
#pragma unroll
        for (int vf = 0; vf < 4; ++vf) oacc[qf][vf] = f32x4{0.f, 0.f, 0.f, 0.f};
    float lsum[2] = {0.f, 0.f};

    u32* const prow0 = &PT[w][0][li][0];
    u32* const prow1 = &PT[w][1][li][0];
    const int g1 = (2 * grp) & 3, g2 = (2 * grp + 1) & 3;
    const int koff = 2 * (grp >> 1);

    // ---- prologue: stage tile 0
    uint4 s0, s1, s2, s3;
    s0 = *(const uint4*)(Kp + (size_t)j0 * 8);
    s1 = *(const uint4*)(Kp + (size_t)j0 * 8 + 8);
    s2 = *(const uint4*)(Vp + (size_t)srow * 1024 + sch * 8);
    s3 = *(const uint4*)(Vp + (size_t)srow * 1024 + sch * 8 + 8);
    KT[0][idx0] = s0; KT[0][idx1] = s1;
    VT[0][idx0] = s2; VT[0][idx1] = s3;
    __syncthreads();

#pragma unroll 2
    for (int kt = 0; kt < 16; ++kt) {
        const int cur = kt & 1;
        // ---- issue next tile's staging loads (covered by this tile's compute)
        if (kt < 15) {
            s0 = *(const uint4*)(Kp + (size_t)(kt + 1) * 4096 + j0 * 8);
            s1 = *(const uint4*)(Kp + (size_t)(kt + 1) * 4096 + j0 * 8 + 8);
            s2 = *(const uint4*)(Vp + (size_t)srow * 1024 + (kt + 1) * 64 + sch * 8);
            s3 = *(const uint4*)(Vp + (size_t)srow * 1024 + (kt + 1) * 64 + sch * 8 + 8);
        }

        // ---- K frags from LDS: A[m=key=kf*16+li][k=c]
        const int x7 = li & 7;
        bf16x8 ak[4][2];
#pragma unroll
        for (int kf = 0; kf < 4; ++kf) {
            const int rb = (kf * 16 + li) * 8;
            ak[kf][0] = ((const BB*)&KT[cur][rb + ((0 + grp) ^ x7)])->v;
            ak[kf][1] = ((const BB*)&KT[cur][rb + ((4 + grp) ^ x7)])->v;
        }
        // ---- S^T = K Q^T : rows=keys (kf*16+grp*4+r), cols=q (li)
        f32x4 sf[2][4];
#pragma unroll
        for (int qf = 0; qf < 2; ++qf)
#pragma unroll
            for (int kf = 0; kf < 4; ++kf) {
                f32x4 acc = f32x4{0.f, 0.f, 0.f, 0.f};
                acc = __builtin_amdgcn_mfma_f32_16x16x32_bf16(ak[kf][0], bq[qf][0], acc, 0, 0, 0);
                acc = __builtin_amdgcn_mfma_f32_16x16x32_bf16(ak[kf][1], bq[qf][1], acc, 0, 0, 0);
                sf[qf][kf] = acc;
            }
        // ---- P = exp2(s*scale - OFF), store to wave-private PT
#pragma unroll
        for (int qf = 0; qf < 2; ++qf) {
            u32 pr[8];
#pragma unroll
            for (int kf = 0; kf < 4; ++kf) {
                float p0 = exp2f(__builtin_fmaf(sf[qf][kf][0], SM_SCALE, -SM_OFF));
                float p1 = exp2f(__builtin_fmaf(sf[qf][kf][1], SM_SCALE, -SM_OFF));
                float p2 = exp2f(__builtin_fmaf(sf[qf][kf][2], SM_SCALE, -SM_OFF));
                float p3 = exp2f(__builtin_fmaf(sf[qf][kf][3], SM_SCALE, -SM_OFF));
                lsum[qf] += (p0 + p1) + (p2 + p3);
                pr[kf * 2 + 0] = pack2(p0, p1);
                pr[kf * 2 + 1] = pack2(p2, p3);
            }
            u32* pw = (qf ? prow1 : prow0) + grp * 8;
            *(uint4*)(pw + 0) = uint4{pr[0], pr[1], pr[2], pr[3]};
            *(uint4*)(pw + 4) = uint4{pr[4], pr[5], pr[6], pr[7]};
        }
        // ---- V frags from LDS: A[m=v=vf*16+li][k=key]
        bf16x8 av[4][2];
#pragma unroll
        for (int vf = 0; vf < 4; ++vf) {
            const int rb = (vf * 16 + li) * 8;
            av[vf][0] = ((const BB*)&VT[cur][rb + ((0 + grp) ^ x7)])->v;
            av[vf][1] = ((const BB*)&VT[cur][rb + ((4 + grp) ^ x7)])->v;
        }
        // ---- O^T += V P : A=V, B=P (read back in A/B k-order)
#pragma unroll
        for (int qf = 0; qf < 2; ++qf) {
            const u32* rp = qf ? prow1 : prow0;
#pragma unroll
            for (int kh = 0; kh < 2; ++kh) {
                uint2 a = *(const uint2*)(rp + g1 * 8 + 4 * kh + koff);
                uint2 b = *(const uint2*)(rp + g2 * 8 + 4 * kh + koff);
                BB pb; pb.u = uint4{a.x, a.y, b.x, b.y};
#pragma unroll
                for (int vf = 0; vf < 4; ++vf)
                    oacc[qf][vf] = __builtin_amdgcn_mfma_f32_16x16x32_bf16(av[vf][kh], pb.v, oacc[qf][vf], 0, 0, 0);
            }
        }
        // ---- commit staged tile, one barrier per iteration
        if (kt < 15) {
            const int nxt = cur ^ 1;
            KT[nxt][idx0] = s0; KT[nxt][idx1] = s1;
            VT[nxt][idx0] = s2; VT[nxt][idx1] = s3;
        }
        __syncthreads();
    }

    // ---- epilogue: l reduce across quads, per-lane scale, 64B-coalesced stores
#pragma unroll
    for (int qf = 0; qf < 2; ++qf) {
        lsum[qf] += __shfl_xor(lsum[qf], 16);
        lsum[qf] += __shfl_xor(lsum[qf], 32);
        float invl = 1.f / lsum[qf];
        float* ob = out + (size_t)pair * 65536 + q0 + qf * 16 + li;
#pragma unroll
        for (int vf = 0; vf < 4; ++vf)
#pragma unroll
            for (int r = 0; r < 4; ++r) {
                int v = vf * 16 + grp * 4 + r;
                ob[(size_t)v * 1024] = oacc[qf][vf][r] * invl;
            }
    }
}

extern "C" void kernel_launch(void* const* d_in, const int* in_sizes, int n_in,
                              void* d_out, int out_size, void* d_ws, size_t ws_size,
                              hipStream_t stream) {
    const float* x     = (const float*)d_in[0];
    const float* gamma = (const float*)d_in[1];
    const float* beta  = (const float*)d_in[2];
    float* out = (float*)d_out;

    float* partials = (float*)d_ws;                       // 3072 f32
    u16* Qn = (u16*)((char*)d_ws + 32768);                // 8.4 MB
    u16* Kn = Qn + (size_t)64 * 65536;                    // 8.4 MB
    u16* Vn = Kn + (size_t)64 * 65536;                    // 8.4 MB (~25.2 MB total)

    gn_partial<<<1536, 256, 0, stream>>>(x, partials);
    pack_kernel<<<1024, 256, 0, stream>>>(x, gamma, beta, partials, Qn, Kn, Vn);
    attn_kernel<<<512, 256, 0, stream>>>(Qn, Kn, Vn, out);
}